// Round 9
// baseline (443.526 us; speedup 1.0000x reference)
//
#include <hip/hip_runtime.h>
#include <cstdint>

#define KDIM 128
#define BATCH 131072
#define CREP 3   // koop_copy internal passes (pushes its dispatch into the top-5 table)
#define NREP 2   // koop_nomem internal passes

typedef __attribute__((ext_vector_type(8))) short short8x;          // MFMA A/B frag
typedef __attribute__((ext_vector_type(4))) float float4x;          // MFMA C/D frag
typedef __attribute__((ext_vector_type(4))) unsigned int uint4x;

// pack two fp32 -> bf16x2 dword, round-half-up (1 add per elem + 1 v_perm)
__device__ __forceinline__ unsigned int pk_bf16(float a, float b) {
    unsigned int ua = __float_as_uint(a) + 0x8000u;
    unsigned int ub = __float_as_uint(b) + 0x8000u;
    return __builtin_amdgcn_perm(ub, ua, 0x07060302u);  // {hi16(b), hi16(a)}
}

__device__ __forceinline__ unsigned short f2bf(float f) {   // RNE, prep kernel only
    unsigned int u = __float_as_uint(f);
    u += 0x7FFFu + ((u >> 16) & 1u);
    return (unsigned short)(u >> 16);
}

// clamped Pade tanh: err<=0.025 abs; y-sensitivity 0.05 -> <1.3e-3 in y. No transcendental.
__device__ __forceinline__ float tanh_pade(float v) {
    float z  = fminf(fmaxf(v, -4.0f), 4.0f);
    float z2 = z * z;
    float num = z * (27.0f + z2);
    float den = fmaf(z2, 9.0f, 27.0f);
    return num * __frcp_rn(den);
}

// direct-to-LDS 16B async copy: LDS dest = (wave-uniform base) + lane*16
__device__ __forceinline__ void gload_lds16(const void* g, void* l) {
    __builtin_amdgcn_global_load_lds(
        (const __attribute__((address_space(1))) void*)g,
        (__attribute__((address_space(3))) void*)l, 16, 0, 0);
}

// Repack W[k][n] fp32 -> fragment-lane-major bf16: coalesced reads, scattered writes.
// Main kernel reads Wf[((nt*4+ks)*64 + lane)*8 + j] = W[ks*32+(lane>>4)*8+j][nt*16+(lane&15)]
__global__ void prep_weights(const float* __restrict__ W1, const float* __restrict__ W2,
                             unsigned short* __restrict__ W1f, unsigned short* __restrict__ W2f) {
    int idx = blockIdx.x * 256 + threadIdx.x;   // 0..16383, coalesced read W[idx]
    int k = idx >> 7, n = idx & 127;
    int ks = k >> 5, j = k & 7;
    int lane = ((k >> 3) & 3) * 16 + (n & 15);
    int nt = n >> 4;
    int dst = ((nt * 4 + ks) * 64 + lane) * 8 + j;
    W1f[dst] = f2bf(W1[idx]);
    W2f[dst] = f2bf(W2[idx]);
}

// ============ ABLATION 1: pure memory path (stage x -> LDS -> store y) ============
// Exact production addressing on both sides; CREP serial passes over distinct tiles.
__global__ __launch_bounds__(256, 3) void koop_copy(const float* __restrict__ x,
                                                    float* __restrict__ y) {
    __shared__ __align__(16) float XY[4][2048];
    const int lane = threadIdx.x & 63;
    const int wave = threadIdx.x >> 6;
    float* Xw = XY[wave];
    #pragma unroll 1
    for (int p = 0; p < CREP; ++p) {
        int blk  = (blockIdx.x + p * 683) & 2047;      // distinct tile per pass
        int row0 = blk * 64 + wave * 16;
        #pragma unroll
        for (int c = 0; c < 8; ++c) {
            int r = c * 2 + (lane >> 5);
            int s = (lane & 31) ^ (r & 7);
            gload_lds16(x + (size_t)(row0 + r) * KDIM + s * 4, &Xw[c * 256]);
        }
        asm volatile("s_waitcnt vmcnt(0)" ::: "memory");
        #pragma unroll
        for (int c = 0; c < 8; ++c) {
            int r  = c * 2 + (lane >> 5);
            int sp = (lane & 31) ^ (r & 7);
            float4 v = *(const float4*)&Xw[c * 256 + lane * 4];
            *(float4*)(y + (size_t)(row0 + r) * KDIM + sp * 4) = v;
        }
        // strict pass boundary: mirrors production's one-shot-per-wave shape
        asm volatile("s_waitcnt vmcnt(0)" ::: "memory");
    }
}

// ============ ABLATION 2: compute chain only (fabricated x, no x/y traffic) ============
__global__ __launch_bounds__(256, 3) void koop_nomem(
        const float* __restrict__ b1, const float* __restrict__ b2,
        const unsigned short* __restrict__ W1f, const unsigned short* __restrict__ W2f) {
    __shared__ __align__(16) float XY[4][2048];
    const int tid  = threadIdx.x;
    const int lane = tid & 63;
    const int wave = tid >> 6;
    const int l15  = lane & 15;
    const int quad = lane >> 4;
    const int Lx   = l15 + ((lane & 16) << 1);
    const bool bhi = (lane & 32) != 0;
    float* Xw = XY[wave];

    #pragma unroll 1
    for (int p = 0; p < NREP; ++p) {
        // fabricated x frags; depend on p to defeat cross-pass CSE/hoisting
        short8x xf[4];
        #pragma unroll
        for (int ks = 0; ks < 4; ++ks) {
            float b0 = (float)(lane + ks * 7 + p * 13) * 0.015625f - 1.0f;
            uint4x u;
            u[0] = pk_bf16(b0, b0 + 0.25f);
            u[1] = pk_bf16(b0 - 0.5f, b0 * 0.75f);
            u[2] = pk_bf16(b0 * 0.5f, b0 - 0.125f);
            u[3] = pk_bf16(b0 + 1.0f, b0 * 1.25f);
            xf[ks] = __builtin_bit_cast(short8x, u);
        }
        // mm1
        float4x acc[8];
        #pragma unroll
        for (int nt = 0; nt < 8; ++nt) acc[nt] = (float4x){0.f, 0.f, 0.f, 0.f};
        #pragma unroll
        for (int ks = 0; ks < 4; ++ks)
            #pragma unroll
            for (int nt = 0; nt < 8; ++nt) {
                short8x w = *(const short8x*)&W1f[((nt * 4 + ks) * 64 + lane) * 8];
                acc[nt] = __builtin_amdgcn_mfma_f32_16x16x32_bf16(w, xf[ks], acc[nt], 0, 0, 0);
            }
        // bias + tanh -> packed bf16
        uint2 d[8];
        #pragma unroll
        for (int nt = 0; nt < 8; ++nt) {
            float4 bb = *(const float4*)&b1[nt * 16 + quad * 4];
            float4x v = acc[nt];
            d[nt].x = pk_bf16(tanh_pade(v[0] + bb.x), tanh_pade(v[1] + bb.y));
            d[nt].y = pk_bf16(tanh_pade(v[2] + bb.z), tanh_pade(v[3] + bb.w));
        }
        // shuffles + mm2
        float4x acc2[8];
        #pragma unroll
        for (int nt = 0; nt < 8; ++nt) acc2[nt] = (float4x){0.f, 0.f, 0.f, 0.f};
        #pragma unroll
        for (int ks = 0; ks < 4; ++ks) {
            uint2 lo = d[2 * ks], hi = d[2 * ks + 1];
            unsigned s0 = (unsigned)__shfl((int)lo.x, Lx);
            unsigned s1 = (unsigned)__shfl((int)lo.y, Lx);
            unsigned s2 = (unsigned)__shfl((int)lo.x, Lx + 16);
            unsigned s3 = (unsigned)__shfl((int)lo.y, Lx + 16);
            unsigned t0 = (unsigned)__shfl((int)hi.x, Lx);
            unsigned t1 = (unsigned)__shfl((int)hi.y, Lx);
            unsigned t2 = (unsigned)__shfl((int)hi.x, Lx + 16);
            unsigned t3 = (unsigned)__shfl((int)hi.y, Lx + 16);
            uint4x u;
            u[0] = bhi ? t0 : s0;
            u[1] = bhi ? t1 : s1;
            u[2] = bhi ? t2 : s2;
            u[3] = bhi ? t3 : s3;
            short8x hf = __builtin_bit_cast(short8x, u);
            #pragma unroll
            for (int nt = 0; nt < 8; ++nt) {
                short8x w = *(const short8x*)&W2f[((nt * 4 + ks) * 64 + lane) * 8];
                acc2[nt] = __builtin_amdgcn_mfma_f32_16x16x32_bf16(w, hf, acc2[nt], 0, 0, 0);
            }
        }
        // epilogue (xv from LDS garbage -- discarded numerics, real op count)
        #pragma unroll
        for (int nt = 0; nt < 8; ++nt) {
            float4 bv = *(const float4*)&b2[nt * 16 + quad * 4];
            int off = l15 * 128 + (((nt * 4 + quad) ^ (l15 & 7)) << 2);
            float4 xv = *(const float4*)&Xw[off];
            float4x v = acc2[nt];
            float4 out;
            {
                float tm = 0.01f * (v[0] + bv.x);
                float tw = 0.01f * (v[1] + bv.y);
                float tm2 = tm * tm, tw2 = tw * tw;
                float ex = fmaf(tm2, fmaf(tm, 0.16666667f, 0.5f), 1.0f + tm);
                float s  = tw * fmaf(tw2, -0.16666667f, 1.0f);
                float c  = fmaf(tw2, -0.5f, 1.0f);
                out.x = ex * fmaf(c, xv.x, -s * xv.y);
                out.y = ex * fmaf(s, xv.x,  c * xv.y);
            }
            {
                float tm = 0.01f * (v[2] + bv.z);
                float tw = 0.01f * (v[3] + bv.w);
                float tm2 = tm * tm, tw2 = tw * tw;
                float ex = fmaf(tm2, fmaf(tm, 0.16666667f, 0.5f), 1.0f + tm);
                float s  = tw * fmaf(tw2, -0.16666667f, 1.0f);
                float c  = fmaf(tw2, -0.5f, 1.0f);
                out.z = ex * fmaf(c, xv.z, -s * xv.w);
                out.w = ex * fmaf(s, xv.z,  c * xv.w);
            }
            *(float4*)&Xw[off] = out;
        }
        // keep-alive: read back LDS so the whole chain stays live (rule #17)
        float keep = 0.f;
        #pragma unroll
        for (int c = 0; c < 8; ++c) keep += Xw[c * 256 + lane * 4];
        asm volatile("" :: "v"(keep));
    }
}

// ============ REAL KERNEL: r8 structure, lb(256,3) (VGPR cap lifted) ============
__global__ __launch_bounds__(256, 3) void koopman_main(
        const float* __restrict__ x, const float* __restrict__ b1,
        const float* __restrict__ b2, const unsigned short* __restrict__ W1f,
        const unsigned short* __restrict__ W2f, float* __restrict__ y) {
    __shared__ __align__(16) float XY[4][2048];   // 8KB/wave x/y stage = 32KB/block

    const int tid  = threadIdx.x;
    const int lane = tid & 63;
    const int wave = tid >> 6;
    const int l15  = lane & 15;
    const int quad = lane >> 4;
    const int Lx   = l15 + ((lane & 16) << 1);
    const bool bhi = (lane & 32) != 0;
    const int row0 = blockIdx.x * 64 + wave * 16;

    float* Xw = XY[wave];

    #pragma unroll
    for (int c = 0; c < 8; ++c) {
        int r = c * 2 + (lane >> 5);
        int s = (lane & 31) ^ (r & 7);
        gload_lds16(x + (size_t)(row0 + r) * KDIM + s * 4, &Xw[c * 256]);
    }
    asm volatile("s_waitcnt vmcnt(0)" ::: "memory");

    short8x xf[4];
    #pragma unroll
    for (int ks = 0; ks < 4; ++ks) {
        int t0 = ks * 8 + quad * 2;
        float4 v0 = *(const float4*)&Xw[l15 * 128 + (((t0    ) ^ (l15 & 7)) << 2)];
        float4 v1 = *(const float4*)&Xw[l15 * 128 + (((t0 + 1) ^ (l15 & 7)) << 2)];
        uint4x u;
        u[0] = pk_bf16(v0.x, v0.y);
        u[1] = pk_bf16(v0.z, v0.w);
        u[2] = pk_bf16(v1.x, v1.y);
        u[3] = pk_bf16(v1.z, v1.w);
        xf[ks] = __builtin_bit_cast(short8x, u);
    }

    float4x acc[8];
    #pragma unroll
    for (int nt = 0; nt < 8; ++nt) acc[nt] = (float4x){0.f, 0.f, 0.f, 0.f};
    #pragma unroll
    for (int ks = 0; ks < 4; ++ks)
        #pragma unroll
        for (int nt = 0; nt < 8; ++nt) {
            short8x w = *(const short8x*)&W1f[((nt * 4 + ks) * 64 + lane) * 8];
            acc[nt] = __builtin_amdgcn_mfma_f32_16x16x32_bf16(w, xf[ks], acc[nt], 0, 0, 0);
        }

    uint2 d[8];
    #pragma unroll
    for (int nt = 0; nt < 8; ++nt) {
        float4 bb = *(const float4*)&b1[nt * 16 + quad * 4];
        float4x v = acc[nt];
        d[nt].x = pk_bf16(tanh_pade(v[0] + bb.x), tanh_pade(v[1] + bb.y));
        d[nt].y = pk_bf16(tanh_pade(v[2] + bb.z), tanh_pade(v[3] + bb.w));
    }

    float4x acc2[8];
    #pragma unroll
    for (int nt = 0; nt < 8; ++nt) acc2[nt] = (float4x){0.f, 0.f, 0.f, 0.f};
    #pragma unroll
    for (int ks = 0; ks < 4; ++ks) {
        uint2 lo = d[2 * ks], hi = d[2 * ks + 1];
        unsigned s0 = (unsigned)__shfl((int)lo.x, Lx);
        unsigned s1 = (unsigned)__shfl((int)lo.y, Lx);
        unsigned s2 = (unsigned)__shfl((int)lo.x, Lx + 16);
        unsigned s3 = (unsigned)__shfl((int)lo.y, Lx + 16);
        unsigned t0 = (unsigned)__shfl((int)hi.x, Lx);
        unsigned t1 = (unsigned)__shfl((int)hi.y, Lx);
        unsigned t2 = (unsigned)__shfl((int)hi.x, Lx + 16);
        unsigned t3 = (unsigned)__shfl((int)hi.y, Lx + 16);
        uint4x u;
        u[0] = bhi ? t0 : s0;
        u[1] = bhi ? t1 : s1;
        u[2] = bhi ? t2 : s2;
        u[3] = bhi ? t3 : s3;
        short8x hf = __builtin_bit_cast(short8x, u);
        #pragma unroll
        for (int nt = 0; nt < 8; ++nt) {
            short8x w = *(const short8x*)&W2f[((nt * 4 + ks) * 64 + lane) * 8];
            acc2[nt] = __builtin_amdgcn_mfma_f32_16x16x32_bf16(w, hf, acc2[nt], 0, 0, 0);
        }
    }

    #pragma unroll
    for (int nt = 0; nt < 8; ++nt) {
        float4 bv = *(const float4*)&b2[nt * 16 + quad * 4];
        int off = l15 * 128 + (((nt * 4 + quad) ^ (l15 & 7)) << 2);
        float4 xv = *(const float4*)&Xw[off];
        float4x v = acc2[nt];
        float4 out;
        {
            float tm = 0.01f * (v[0] + bv.x);
            float tw = 0.01f * (v[1] + bv.y);
            float tm2 = tm * tm, tw2 = tw * tw;
            float ex = fmaf(tm2, fmaf(tm, 0.16666667f, 0.5f), 1.0f + tm);
            float s  = tw * fmaf(tw2, -0.16666667f, 1.0f);
            float c  = fmaf(tw2, -0.5f, 1.0f);
            out.x = ex * fmaf(c, xv.x, -s * xv.y);
            out.y = ex * fmaf(s, xv.x,  c * xv.y);
        }
        {
            float tm = 0.01f * (v[2] + bv.z);
            float tw = 0.01f * (v[3] + bv.w);
            float tm2 = tm * tm, tw2 = tw * tw;
            float ex = fmaf(tm2, fmaf(tm, 0.16666667f, 0.5f), 1.0f + tm);
            float s  = tw * fmaf(tw2, -0.16666667f, 1.0f);
            float c  = fmaf(tw2, -0.5f, 1.0f);
            out.z = ex * fmaf(c, xv.z, -s * xv.w);
            out.w = ex * fmaf(s, xv.z,  c * xv.w);
        }
        *(float4*)&Xw[off] = out;
    }

    #pragma unroll
    for (int c = 0; c < 8; ++c) {
        int r  = c * 2 + (lane >> 5);
        int sp = (lane & 31) ^ (r & 7);
        float4 v = *(const float4*)&Xw[c * 256 + lane * 4];
        *(float4*)(y + (size_t)(row0 + r) * KDIM + sp * 4) = v;
    }
}

extern "C" void kernel_launch(void* const* d_in, const int* in_sizes, int n_in,
                              void* d_out, int out_size, void* d_ws, size_t ws_size,
                              hipStream_t stream) {
    const float* x  = (const float*)d_in[0];
    const float* W1 = (const float*)d_in[1];
    const float* b1 = (const float*)d_in[2];
    const float* W2 = (const float*)d_in[3];
    const float* b2 = (const float*)d_in[4];
    float* y = (float*)d_out;

    unsigned short* W1f = (unsigned short*)d_ws;
    unsigned short* W2f = W1f + 128 * 128;

    prep_weights<<<64, 256, 0, stream>>>(W1, W2, W1f, W2f);
    // ablation dispatches (outputs junk / overwritten; real kernel runs last)
    koop_copy <<<BATCH / 64, 256, 0, stream>>>(x, y);
    koop_nomem<<<BATCH / 64, 256, 0, stream>>>(b1, b2, W1f, W2f);
    // real kernel: produces the graded y
    koopman_main<<<BATCH / 64, 256, 0, stream>>>(x, b1, b2, W1f, W2f, y);
}

// Round 10
// 138.097 us; speedup vs baseline: 3.2117x; 3.2117x over previous
//
#include <hip/hip_runtime.h>
#include <cstdint>

#define KDIM 128
#define BATCH 131072

typedef __attribute__((ext_vector_type(8))) short short8x;          // MFMA A/B frag
typedef __attribute__((ext_vector_type(4))) float float4x;          // MFMA C/D frag
typedef __attribute__((ext_vector_type(4))) unsigned int uint4x;

// pack two fp32 -> bf16x2 dword, round-half-up (1 add per elem + 1 v_perm)
__device__ __forceinline__ unsigned int pk_bf16(float a, float b) {
    unsigned int ua = __float_as_uint(a) + 0x8000u;
    unsigned int ub = __float_as_uint(b) + 0x8000u;
    return __builtin_amdgcn_perm(ub, ua, 0x07060302u);  // {hi16(b), hi16(a)}
}

__device__ __forceinline__ unsigned short f2bf(float f) {   // RNE, prep kernel only
    unsigned int u = __float_as_uint(f);
    u += 0x7FFFu + ((u >> 16) & 1u);
    return (unsigned short)(u >> 16);
}

// clamped Pade tanh: err<=0.025 abs; y-sensitivity 0.05 -> <1.3e-3 in y. No transcendental.
__device__ __forceinline__ float tanh_pade(float v) {
    float z  = fminf(fmaxf(v, -4.0f), 4.0f);
    float z2 = z * z;
    float num = z * (27.0f + z2);
    float den = fmaf(z2, 9.0f, 27.0f);
    return num * __frcp_rn(den);
}

// direct-to-LDS 16B async copy: LDS dest = (wave-uniform base) + lane*16
__device__ __forceinline__ void gload_lds16(const void* g, void* l) {
    __builtin_amdgcn_global_load_lds(
        (const __attribute__((address_space(1))) void*)g,
        (__attribute__((address_space(3))) void*)l, 16, 0, 0);
}

// Repack W[k][n] fp32 -> fragment-lane-major bf16: coalesced reads, scattered writes.
// Main kernel reads Wf[((nt*4+ks)*64 + lane)*8 + j] = W[ks*32+(lane>>4)*8+j][nt*16+(lane&15)]
__global__ void prep_weights(const float* __restrict__ W1, const float* __restrict__ W2,
                             unsigned short* __restrict__ W1f, unsigned short* __restrict__ W2f) {
    int idx = blockIdx.x * 256 + threadIdx.x;   // 0..16383, coalesced read W[idx]
    int k = idx >> 7, n = idx & 127;
    int ks = k >> 5, j = k & 7;
    int lane = ((k >> 3) & 3) * 16 + (n & 15);
    int nt = n >> 4;
    int dst = ((nt * 4 + ks) * 64 + lane) * 8 + j;
    W1f[dst] = f2bf(W1[idx]);
    W2f[dst] = f2bf(W2[idx]);
}

// Two-tile-per-wave interleaved pipeline (r9 ablation: memory path=31us, +15us serial
// compute). stage A + stage B + W1-ks0 frags all in flight before any wait; vmcnt(16)
// releases compute A (B's latency hides under it); vmcnt(8) releases compute B (only
// the 8 newest ops -- A's stores -- may linger => stage B retired). wf0 (W1 ks0) is
// tile-invariant: loaded once, lives in 32 VGPRs across both tiles.
__global__ __launch_bounds__(256, 2) void koopman_main(
        const float* __restrict__ x, const float* __restrict__ b1,
        const float* __restrict__ b2, const unsigned short* __restrict__ W1f,
        const unsigned short* __restrict__ W2f, float* __restrict__ y) {
    __shared__ __align__(16) float XY[4][2][2048];   // 2 x 8KB per wave = 64KB/block

    const int tid  = threadIdx.x;
    const int lane = tid & 63;
    const int wave = tid >> 6;
    const int l15  = lane & 15;
    const int quad = lane >> 4;
    const int Lx   = l15 + ((lane & 16) << 1);   // shuffle src: l15 + 32a
    const bool bhi = (lane & 32) != 0;
    const int row0A = blockIdx.x * 128 + wave * 32;
    const int row0B = row0A + 16;

    float* XA = &XY[wave][0][0];
    float* XB = &XY[wave][1][0];

    // one tile's full compute + y-store (r9-verified body); wf0 = preloaded W1-ks0 frags
    short8x wf0[8];
    auto compute_store = [&](float* Xw, int row0) {
        // pack bf16 B-frags (X^T): lane reads row l15, slots ks*8+quad*2, +1
        short8x xf[4];
        #pragma unroll
        for (int ks = 0; ks < 4; ++ks) {
            int t0 = ks * 8 + quad * 2;
            float4 v0 = *(const float4*)&Xw[l15 * 128 + (((t0    ) ^ (l15 & 7)) << 2)];
            float4 v1 = *(const float4*)&Xw[l15 * 128 + (((t0 + 1) ^ (l15 & 7)) << 2)];
            uint4x u;
            u[0] = pk_bf16(v0.x, v0.y);
            u[1] = pk_bf16(v0.z, v0.w);
            u[2] = pk_bf16(v1.x, v1.y);
            u[3] = pk_bf16(v1.z, v1.w);
            xf[ks] = __builtin_bit_cast(short8x, u);
        }
        // matmul 1 (ks0 uses the preloaded wf0 frags)
        float4x acc[8];
        #pragma unroll
        for (int nt = 0; nt < 8; ++nt) acc[nt] = (float4x){0.f, 0.f, 0.f, 0.f};
        #pragma unroll
        for (int ks = 0; ks < 4; ++ks)
            #pragma unroll
            for (int nt = 0; nt < 8; ++nt) {
                short8x w = (ks == 0) ? wf0[nt]
                          : *(const short8x*)&W1f[((nt * 4 + ks) * 64 + lane) * 8];
                acc[nt] = __builtin_amdgcn_mfma_f32_16x16x32_bf16(w, xf[ks], acc[nt], 0, 0, 0);
            }
        // bias + tanh -> packed bf16 pairs in registers
        uint2 d[8];
        #pragma unroll
        for (int nt = 0; nt < 8; ++nt) {
            float4 bb = *(const float4*)&b1[nt * 16 + quad * 4];
            float4x v = acc[nt];
            d[nt].x = pk_bf16(tanh_pade(v[0] + bb.x), tanh_pade(v[1] + bb.y));
            d[nt].y = pk_bf16(tanh_pade(v[2] + bb.z), tanh_pade(v[3] + bb.w));
        }
        // matmul 2: B-frags via quad shuffles (verified round 3)
        float4x acc2[8];
        #pragma unroll
        for (int nt = 0; nt < 8; ++nt) acc2[nt] = (float4x){0.f, 0.f, 0.f, 0.f};
        #pragma unroll
        for (int ks = 0; ks < 4; ++ks) {
            uint2 lo = d[2 * ks], hi = d[2 * ks + 1];
            unsigned s0 = (unsigned)__shfl((int)lo.x, Lx);
            unsigned s1 = (unsigned)__shfl((int)lo.y, Lx);
            unsigned s2 = (unsigned)__shfl((int)lo.x, Lx + 16);
            unsigned s3 = (unsigned)__shfl((int)lo.y, Lx + 16);
            unsigned t0 = (unsigned)__shfl((int)hi.x, Lx);
            unsigned t1 = (unsigned)__shfl((int)hi.y, Lx);
            unsigned t2 = (unsigned)__shfl((int)hi.x, Lx + 16);
            unsigned t3 = (unsigned)__shfl((int)hi.y, Lx + 16);
            uint4x u;
            u[0] = bhi ? t0 : s0;
            u[1] = bhi ? t1 : s1;
            u[2] = bhi ? t2 : s2;
            u[3] = bhi ? t3 : s3;
            short8x hf = __builtin_bit_cast(short8x, u);
            #pragma unroll
            for (int nt = 0; nt < 8; ++nt) {
                short8x w = *(const short8x*)&W2f[((nt * 4 + ks) * 64 + lane) * 8];
                acc2[nt] = __builtin_amdgcn_mfma_f32_16x16x32_bf16(w, hf, acc2[nt], 0, 0, 0);
            }
        }
        // fused epilogue, in-place in LDS
        #pragma unroll
        for (int nt = 0; nt < 8; ++nt) {
            float4 bv = *(const float4*)&b2[nt * 16 + quad * 4];
            int off = l15 * 128 + (((nt * 4 + quad) ^ (l15 & 7)) << 2);
            float4 xv = *(const float4*)&Xw[off];
            float4x v = acc2[nt];
            float4 out;
            {
                float tm = 0.01f * (v[0] + bv.x);
                float tw = 0.01f * (v[1] + bv.y);
                float tm2 = tm * tm, tw2 = tw * tw;
                float ex = fmaf(tm2, fmaf(tm, 0.16666667f, 0.5f), 1.0f + tm);
                float s  = tw * fmaf(tw2, -0.16666667f, 1.0f);
                float c  = fmaf(tw2, -0.5f, 1.0f);
                out.x = ex * fmaf(c, xv.x, -s * xv.y);
                out.y = ex * fmaf(s, xv.x,  c * xv.y);
            }
            {
                float tm = 0.01f * (v[2] + bv.z);
                float tw = 0.01f * (v[3] + bv.w);
                float tm2 = tm * tm, tw2 = tw * tw;
                float ex = fmaf(tm2, fmaf(tm, 0.16666667f, 0.5f), 1.0f + tm);
                float s  = tw * fmaf(tw2, -0.16666667f, 1.0f);
                float c  = fmaf(tw2, -0.5f, 1.0f);
                out.z = ex * fmaf(c, xv.z, -s * xv.w);
                out.w = ex * fmaf(s, xv.z,  c * xv.w);
            }
            *(float4*)&Xw[off] = out;
        }
        // y store: linear LDS read; global dst carries inverse swizzle (cached path)
        #pragma unroll
        for (int c = 0; c < 8; ++c) {
            int r  = c * 2 + (lane >> 5);
            int sp = (lane & 31) ^ (r & 7);
            float4 v = *(const float4*)&Xw[c * 256 + lane * 4];
            *(float4*)(y + (size_t)(row0 + r) * KDIM + sp * 4) = v;
        }
    };

    // ---- pipeline prologue: stage A | pin | stage B + wf0 (24 vm ops in flight) ----
    #pragma unroll
    for (int c = 0; c < 8; ++c) {
        int r = c * 2 + (lane >> 5);
        int s = (lane & 31) ^ (r & 7);
        gload_lds16(x + (size_t)(row0A + r) * KDIM + s * 4, &XA[c * 256]);
    }
    asm volatile("" ::: "memory");          // pin: A's 8 ops are strictly oldest
    #pragma unroll
    for (int c = 0; c < 8; ++c) {
        int r = c * 2 + (lane >> 5);
        int s = (lane & 31) ^ (r & 7);
        gload_lds16(x + (size_t)(row0B + r) * KDIM + s * 4, &XB[c * 256]);
    }
    #pragma unroll
    for (int nt = 0; nt < 8; ++nt)          // W1 ks0 frags, tile-invariant
        wf0[nt] = *(const short8x*)&W1f[((nt * 4 + 0) * 64 + lane) * 8];

    // ---- wait A only: exactly 16 newer ops (stage B + wf0) may remain in flight ----
    asm volatile("s_waitcnt vmcnt(16)" ::: "memory");
    compute_store(XA, row0A);

    // ---- wait B: all but the 8 newest (A's stores) retired => stage B landed ----
    asm volatile("s_waitcnt vmcnt(8)" ::: "memory");
    compute_store(XB, row0B);
}

extern "C" void kernel_launch(void* const* d_in, const int* in_sizes, int n_in,
                              void* d_out, int out_size, void* d_ws, size_t ws_size,
                              hipStream_t stream) {
    const float* x  = (const float*)d_in[0];
    const float* W1 = (const float*)d_in[1];
    const float* b1 = (const float*)d_in[2];
    const float* W2 = (const float*)d_in[3];
    const float* b2 = (const float*)d_in[4];
    float* y = (float*)d_out;

    unsigned short* W1f = (unsigned short*)d_ws;
    unsigned short* W2f = W1f + 128 * 128;

    prep_weights<<<64, 256, 0, stream>>>(W1, W2, W1f, W2f);
    koopman_main<<<BATCH / 128, 256, 0, stream>>>(x, b1, b2, W1f, W2f, y);
}